// Round 1
// baseline (326.190 us; speedup 1.0000x reference)
//
#include <hip/hip_runtime.h>
#include <hip/hip_bf16.h>

#define DD 64
#define UU_ 1024
#define BATCH 4096
#define ROWS 16
#define NBLK (BATCH / ROWS)   // 256
#define NTHR 512

typedef __attribute__((ext_vector_type(8))) short bf16x8;
typedef __attribute__((ext_vector_type(4))) float f32x4;

// dh-group helpers: group g (=degree) has cnt(g) units; prefix offset off1(g)
__host__ __device__ __forceinline__ int off1(int g) { return (g <= 16) ? 17 * g : 16 * g + 16; }
__host__ __device__ __forceinline__ int cntg(int g) { return (g < 16) ? 17 : 16; }

// ---------------- prep: pack masked/permuted weights into d_ws ----------------
// W1b [2048 slots][1024 k] bf16 : slot = 32*g + j (j<cnt(g) real, else 0);
//   k = packed h1 slot (dh-sorted); value = W1[u= g+63j][w=perm(k)] if k < c(g) else 0.
// W2q [63*17][128] f32 : W2q[(g*17+j)*128 + r] = W2[r][g+63j] (j<cnt(g), else 0).
__global__ void prep_kernel(const float* __restrict__ W1, const float* __restrict__ W2,
                            unsigned short* __restrict__ W1b, float* __restrict__ W2q) {
    long idx = (long)blockIdx.x * blockDim.x + threadIdx.x;
    const long NW1 = 2048L * 1024;
    if (idx < NW1) {
        int slot = (int)(idx >> 10), k = (int)(idx & 1023);
        int g = slot >> 5, j = slot & 31;
        float val = 0.f;
        if (g < 63 && j < cntg(g) && k < off1(g + 1)) {
            int u = g + 63 * j;
            int gk, jk;
            if (k < 272) { gk = k / 17; jk = k - gk * 17; }
            else         { gk = (k >> 4) - 1; jk = k & 15; }
            int w = gk + 63 * jk;
            val = W1[u * 1024 + w];
        }
        __hip_bfloat16 hb = __float2bfloat16(val);
        W1b[idx] = *reinterpret_cast<unsigned short*>(&hb);
    } else {
        long widx = idx - NW1;
        if (widx < 1071L * 128) {
            int r = (int)(widx & 127);
            int t2 = (int)(widx >> 7);
            int g = t2 / 17, j = t2 - g * 17;
            float val = 0.f;
            if (j < cntg(g)) val = W2[r * 1024 + g + 63 * j];
            W2q[t2 * 128 + r] = val;
        }
    }
}

// ---------------- main: 64 sequential steps, 16 rows per block ----------------
__global__ __launch_bounds__(NTHR) void made_kernel(
    const float* __restrict__ uin, const float* __restrict__ W0,
    const float* __restrict__ b0, const float* __restrict__ b1,
    const float* __restrict__ b2, const unsigned short* __restrict__ W1b,
    const float* __restrict__ W2q, float* __restrict__ out) {

    __shared__ __align__(16) float xL[ROWS][68];              // fp32 x, padded stride
    __shared__ __align__(16) unsigned short h1L[ROWS][1032];  // bf16 h1, dh-packed (1024 + pad)
    __shared__ __align__(16) float h2buf[ROWS][20];           // new h2 group (fp32)
    __shared__ __align__(16) float scratch[8 * 2 * 256];      // MFMA K-split partials (16 KB)
    __shared__ float zred[ROWS][2];

    const int t = threadIdx.x;
    const int lane = t & 63;
    const int wv = t >> 6;  // wave 0..7
    const int rowbase = blockIdx.x * ROWS;

    // zero h1L (slots beyond prefix must read as 0 for padded MFMA K-tiles)
    for (int idx = t; idx < ROWS * 1032 / 2; idx += NTHR)
        ((unsigned int*)h1L)[idx] = 0u;

    const int s1row = t & 15, s1j = t >> 4;   // stage-1 map
    const int am = lane & 15, aq = lane >> 4; // MFMA fragment map
    const int zrow = t & 15, rg = t >> 4;     // z-update map: owns r = 4*rg..4*rg+3

    f32x4 zacc = {0.f, 0.f, 0.f, 0.f};
    float ldj = 0.f;

    __syncthreads();

    for (int i = 0; i < 64; ++i) {
        const int g = i - 1;

        // ---- stage 1: new h1 group g (17/16 units, dot over x[0..i-1]) ----
        if (i > 0 && s1j < cntg(g)) {
            int uu = g + 63 * s1j;
            const float* w0r = W0 + uu * 64;
            f32x4 acc = {0.f, 0.f, 0.f, 0.f};
            int d = 0;
            for (; d + 4 <= i; d += 4) {
                float4 xv = *(const float4*)&xL[s1row][d];
                float4 wv4 = *(const float4*)&w0r[d];
                acc[0] += xv.x * wv4.x; acc[1] += xv.y * wv4.y;
                acc[2] += xv.z * wv4.z; acc[3] += xv.w * wv4.w;
            }
            float a = acc[0] + acc[1] + acc[2] + acc[3];
            for (; d < i; ++d) a += xL[s1row][d] * w0r[d];
            a += b0[uu];
            a = a > 0.f ? a : 0.f;
            __hip_bfloat16 hb = __float2bfloat16(a);
            h1L[s1row][off1(g) + s1j] = *reinterpret_cast<unsigned short*>(&hb);
        }
        __syncthreads();

        // ---- stage 2: new h2 group via MFMA, K-split over 8 waves ----
        if (i > 0) {
            const int c = off1(g + 1);            // true K extent
            const int Ktiles = (c + 31) >> 5;
            f32x4 acc0 = {0.f, 0.f, 0.f, 0.f}, acc1 = {0.f, 0.f, 0.f, 0.f};
            const unsigned short* brow0 = W1b + (size_t)(32 * g + am) * 1024;
            const unsigned short* brow1 = brow0 + 16 * 1024;
            for (int kt = wv; kt < Ktiles; kt += 8) {
                int kb = kt * 32 + aq * 8;
                bf16x8 af  = *(const bf16x8*)&h1L[am][kb];
                bf16x8 bf0 = *(const bf16x8*)&brow0[kb];
                bf16x8 bf1 = *(const bf16x8*)&brow1[kb];
                acc0 = __builtin_amdgcn_mfma_f32_16x16x32_bf16(af, bf0, acc0, 0, 0, 0);
                acc1 = __builtin_amdgcn_mfma_f32_16x16x32_bf16(af, bf1, acc1, 0, 0, 0);
            }
            float* sc = scratch + wv * 512;
#pragma unroll
            for (int r = 0; r < 4; ++r) {
                sc[r * 64 + lane] = acc0[r];
                sc[256 + r * 64 + lane] = acc1[r];
            }
        }
        __syncthreads();

        // ---- reduce partials -> h2buf (bias + relu) ----
        if (i > 0) {
            int tile = t >> 8, m = (t >> 4) & 15, n = t & 15;
            int j = tile * 16 + n;
            if (j < cntg(g)) {
                int base = tile * 256 + (m & 3) * 64 + (m >> 2) * 16 + n;
                float s = 0.f;
#pragma unroll
                for (int w = 0; w < 8; ++w) s += scratch[w * 512 + base];
                s += b1[g + 63 * j];
                h2buf[m][j] = s > 0.f ? s : 0.f;
            }
        }
        __syncthreads();

        // ---- z accumulator rank-17 update + publish z_i, sigma_i ----
        if (i > 0) {
            const int cg = cntg(g);
            const float* wq = W2q + (size_t)g * 17 * 128 + rg * 4;
            for (int j = 0; j < cg; ++j) {
                float hv = h2buf[zrow][j];
                float4 wv4 = *(const float4*)&wq[j * 128];
                zacc[0] += hv * wv4.x; zacc[1] += hv * wv4.y;
                zacc[2] += hv * wv4.z; zacc[3] += hv * wv4.w;
            }
        }
        {
            int sel = i & 3;
            float pub = sel == 0 ? zacc[0] : (sel == 1 ? zacc[1] : (sel == 2 ? zacc[2] : zacc[3]));
            if (rg == (i >> 2)) zred[zrow][0] = pub;          // r = i      (mu)
            if (rg == 16 + (i >> 2)) zred[zrow][1] = pub;     // r = 64 + i (sigma)
        }
        __syncthreads();

        // ---- x update ----
        if (t < 16) {
            float mu = zred[t][0] + b2[i];
            float sg = zred[t][1] + b2[64 + i];
            float xv = uin[(size_t)(rowbase + t) * 64 + i] * __expf(sg) + mu;
            xL[t][i] = xv;
            out[(size_t)(rowbase + t) * 64 + i] = xv;
            ldj += sg;
        }
        __syncthreads();
    }

    if (t < 16) out[(size_t)BATCH * 64 + rowbase + t] = ldj;
}

extern "C" void kernel_launch(void* const* d_in, const int* in_sizes, int n_in,
                              void* d_out, int out_size, void* d_ws, size_t ws_size,
                              hipStream_t stream) {
    (void)in_sizes; (void)n_in; (void)out_size; (void)ws_size;
    const float* u  = (const float*)d_in[0];
    const float* W0 = (const float*)d_in[1];
    const float* b0 = (const float*)d_in[2];
    const float* W1 = (const float*)d_in[3];
    const float* b1 = (const float*)d_in[4];
    const float* W2 = (const float*)d_in[5];
    const float* b2 = (const float*)d_in[6];
    float* out = (float*)d_out;

    unsigned short* W1b = (unsigned short*)d_ws;                    // 4 MB
    float* W2q = (float*)((char*)d_ws + 2048L * 1024 * 2);          // 548 KB

    long total = 2048L * 1024 + 1071L * 128;
    int thr = 256;
    long blocks = (total + thr - 1) / thr;
    prep_kernel<<<dim3((unsigned)blocks), dim3(thr), 0, stream>>>(W1, W2, W1b, W2q);
    made_kernel<<<dim3(NBLK), dim3(NTHR), 0, stream>>>(u, W0, b0, b1, b2, W1b, W2q, out);
}

// Round 2
// 239.826 us; speedup vs baseline: 1.3601x; 1.3601x over previous
//
#include <hip/hip_runtime.h>
#include <hip/hip_bf16.h>

#define BATCH 4096
#define NTHR 512

typedef __attribute__((ext_vector_type(8))) short bf16x8;
typedef __attribute__((ext_vector_type(4))) float f32x4;

// dh-sorted packing: group g (= degree) has cnt(g) units, prefix off1(g)
__host__ __device__ __forceinline__ int off1(int g) { return (g <= 16) ? 17 * g : 16 * g + 16; }
__host__ __device__ __forceinline__ int cntg(int g) { return (g < 16) ? 17 : 16; }
// packed slot p -> original unit index u = gp + 63*jp
__host__ __device__ __forceinline__ int unitOf(int p) {
    int gp, jp;
    if (p < 272) { gp = p / 17; jp = p - gp * 17; }
    else         { gp = (p >> 4) - 1; jp = p & 15; }
    return gp + 63 * jp;
}
__device__ __forceinline__ short f2bf(float f) {
    __hip_bfloat16 h = __float2bfloat16(f);
    return *reinterpret_cast<short*>(&h);
}

// ---------------- prep: pack weights into MFMA-B-fragment-friendly layouts ----------------
// W1f [g][tile(64)][lane(64)][e(8)] bf16 : B[k=(lane>>4)*8+e][n=lane&15] for out-slot p=tile*16+n,
//     value = k<cnt(g) ? W1[unitOf(p)][g+63k] : 0
// W2f [g][wave(8)][lane(64)][e(8)] bf16 : r = wave*16+n, value = k<cnt(g) ? W2[r][g+63k] : 0
// W0p [d(64)][p(1024)] bf16 : W0[unitOf(p)][d]
// b0p/b1p [1024] f32 : biases in packed order
#define N_W1F (63L * 64 * 64 * 8)          // 2,064,384
#define N_W2F (63L * 8 * 64 * 8)           //   258,048
#define N_W0P (64L * 1024)                 //    65,536
#define PREP_TOTAL (N_W1F + N_W2F + N_W0P + 1024 + 1024)

__global__ void prep2(const float* __restrict__ W0, const float* __restrict__ b0,
                      const float* __restrict__ W1, const float* __restrict__ b1,
                      const float* __restrict__ W2,
                      short* __restrict__ W1f, short* __restrict__ W2f,
                      short* __restrict__ W0p, float* __restrict__ b0p,
                      float* __restrict__ b1p) {
    long idx = (long)blockIdx.x * blockDim.x + threadIdx.x;
    if (idx < N_W1F) {
        int e = (int)(idx & 7), lane = (int)((idx >> 3) & 63);
        int tile = (int)((idx >> 9) & 63), g = (int)(idx >> 15);
        int k = ((lane >> 4) << 3) + e;
        int p = tile * 16 + (lane & 15);
        float v = 0.f;
        if (k < cntg(g)) v = W1[(long)unitOf(p) * 1024 + g + 63 * k];
        W1f[idx] = f2bf(v);
    } else if (idx < N_W1F + N_W2F) {
        long q = idx - N_W1F;
        int e = (int)(q & 7), lane = (int)((q >> 3) & 63);
        int w = (int)((q >> 9) & 7), g = (int)(q >> 12);
        int k = ((lane >> 4) << 3) + e;
        int r = w * 16 + (lane & 15);
        float v = 0.f;
        if (k < cntg(g)) v = W2[(long)r * 1024 + g + 63 * k];
        W2f[q] = f2bf(v);
    } else if (idx < N_W1F + N_W2F + N_W0P) {
        long q = idx - (N_W1F + N_W2F);
        int p = (int)(q & 1023), d = (int)(q >> 10);
        W0p[q] = f2bf(W0[(long)unitOf(p) * 64 + d]);
    } else if (idx < N_W1F + N_W2F + N_W0P + 1024) {
        int p = (int)(idx - (N_W1F + N_W2F + N_W0P));
        b0p[p] = b0[unitOf(p)];
    } else if (idx < PREP_TOTAL) {
        int p = (int)(idx - (N_W1F + N_W2F + N_W0P + 1024));
        b1p[p] = b1[unitOf(p)];
    }
}

// ---------------- main: incremental MFMA pipeline, 3 barriers/step ----------------
__global__ __launch_bounds__(NTHR) void made2(
    const float* __restrict__ uin, const float* __restrict__ b2,
    const short* __restrict__ W1f, const short* __restrict__ W2f,
    const short* __restrict__ W0p, const float* __restrict__ b0p,
    const float* __restrict__ b1p, float* __restrict__ out) {

    __shared__ __align__(16) short h1g[16][40];   // group-g h1 (bf16), A-frag layout, padded stride
    __shared__ __align__(16) short h2g[16][40];   // group-g h2 (bf16)
    __shared__ float uL[16][65];                  // preloaded u
    __shared__ float xLs[16][65];                 // x staged for final coalesced store
    __shared__ float zred[16][2];                 // published (mu_raw, sigma_raw)

    const int t = threadIdx.x, lane = t & 63, wv = t >> 6;
    const int n = lane & 15, aq = lane >> 4;
    const int rowbase = blockIdx.x * 16;

    for (int idx = t; idx < 16 * 40; idx += NTHR) { (&h1g[0][0])[idx] = 0; (&h2g[0][0])[idx] = 0; }
    if (t < 256) {
        int r = t >> 4, c = (t & 15) * 4;
        float4 v = *(const float4*)&uin[(long)(rowbase + r) * 64 + c];
        uL[r][c] = v.x; uL[r][c + 1] = v.y; uL[r][c + 2] = v.z; uL[r][c + 3] = v.w;
    }

    // persistent accumulators: pre1/pre2 tiles (wave wv owns packed-slot tiles wv*8..wv*8+7),
    // zacc = z columns r in [wv*16, wv*16+16)
    f32x4 acc1[8], acc2[8], zacc;
#pragma unroll
    for (int s = 0; s < 8; ++s) { acc1[s] = (f32x4){0,0,0,0}; acc2[s] = (f32x4){0,0,0,0}; }
    zacc = (f32x4){0,0,0,0};

    // single-buffered prefetch registers (reissued right after consumption)
    bf16x8 w1f[8]; bf16x8 w2f; short w0s[8];
#pragma unroll
    for (int s = 0; s < 8; ++s) {
        w0s[s] = W0p[(wv * 8 + s) * 16 + n];                                   // d=0
        w1f[s] = *(const bf16x8*)&W1f[(((long)0 * 64 + wv * 8 + s) * 64 + lane) * 8]; // g=0
    }
    w2f = *(const bf16x8*)&W2f[(((long)0 * 8 + wv) * 64 + lane) * 8];          // g=0

    float xreg = 0.f, ldj = 0.f;
    __syncthreads();

#pragma unroll 1
    for (int i = 0; i < 64; ++i) {
        const int g = i - 1;
        const int og = (g >= 0) ? off1(g) : 0;
        const int cg = (g >= 0) ? cntg(g) : 0;

        // bias candidates for this step's finalizes (L2-hot 4KB arrays, issued early)
        float b0a = 0.f, b0b = 0.f, b1a = 0.f, b1b = 0.f;
        if (g >= 0) {
            int p0 = og + ((n - og) & 15);
            b0a = b0p[p0]; b1a = b1p[p0];
            int p1 = p0 + 16;
            if (p1 < 1024) { b0b = b0p[p1]; b1b = b1p[p1]; }
        }
        const float b2m = b2[i], b2s = b2[64 + i];

        // ---- S1: pre1 += x_{i-1} (rank-1 via MFMA), then finalize h1 group g ----
        if (g >= 0) {
            bf16x8 af = {0, 0, 0, 0, 0, 0, 0, 0};
            if (aq == 0) af[0] = f2bf(xreg);   // A[m][k=0] = x[m]
#pragma unroll
            for (int s = 0; s < 8; ++s) {
                const int tile = wv * 8 + s;
                if (tile * 16 + 16 > og) {
                    bf16x8 bfr = {0, 0, 0, 0, 0, 0, 0, 0};
                    if (aq == 0) bfr[0] = w0s[s];  // B[0][n] = W0p[d=i-1][tile*16+n]
                    acc1[s] = __builtin_amdgcn_mfma_f32_16x16x32_bf16(af, bfr, acc1[s], 0, 0, 0);
                }
            }
            if (i < 63) {   // prefetch W0 row d=i for step i+1
#pragma unroll
                for (int s = 0; s < 8; ++s)
                    w0s[s] = W0p[i * 1024 + (wv * 8 + s) * 16 + n];
            }
            // finalize: relu(acc + b0) -> h1g (group slots are 1-2 contiguous tiles)
#pragma unroll
            for (int s = 0; s < 8; ++s) {
                const int tile = wv * 8 + s;
                const int p = tile * 16 + n;
                if (p >= og && p < og + 17) {
                    const int j = p - og;
                    const float bb = (j < 16) ? b0a : b0b;
#pragma unroll
                    for (int r = 0; r < 4; ++r) {
                        float v = (j < cg) ? (acc1[s][r] + bb) : 0.f;
                        v = v > 0.f ? v : 0.f;
                        h1g[aq * 4 + r][j] = f2bf(v);
                    }
                }
            }
        }
        __syncthreads();   // A: h1g visible

        // ---- S2: pre2 += h1_group_g * W1 (active tiles), finalize h2 group g ----
        if (g >= 0) {
            const bf16x8 af2 = *(const bf16x8*)&h1g[n][aq * 8];
#pragma unroll
            for (int s = 0; s < 8; ++s) {
                const int tile = wv * 8 + s;
                if (tile * 16 + 16 > og)
                    acc2[s] = __builtin_amdgcn_mfma_f32_16x16x32_bf16(af2, w1f[s], acc2[s], 0, 0, 0);
            }
            if (i < 63) {   // prefetch W1f for g'=i (only tiles that will be active)
                const int ogn = off1(i);
#pragma unroll
                for (int s = 0; s < 8; ++s) {
                    const int tile = wv * 8 + s;
                    if (tile * 16 + 16 > ogn)
                        w1f[s] = *(const bf16x8*)&W1f[(((long)i * 64 + tile) * 64 + lane) * 8];
                }
            }
#pragma unroll
            for (int s = 0; s < 8; ++s) {
                const int tile = wv * 8 + s;
                const int p = tile * 16 + n;
                if (p >= og && p < og + 17) {
                    const int j = p - og;
                    const float bb = (j < 16) ? b1a : b1b;
#pragma unroll
                    for (int r = 0; r < 4; ++r) {
                        float v = (j < cg) ? (acc2[s][r] + bb) : 0.f;
                        v = v > 0.f ? v : 0.f;
                        h2g[aq * 4 + r][j] = f2bf(v);
                    }
                }
            }
        }
        __syncthreads();   // B: h2g visible

        // ---- S3: zacc += h2_group_g * W2 (one MFMA/wave), publish mu_i/sigma_i ----
        if (g >= 0) {
            const bf16x8 af3 = *(const bf16x8*)&h2g[n][aq * 8];
            zacc = __builtin_amdgcn_mfma_f32_16x16x32_bf16(af3, w2f, zacc, 0, 0, 0);
            if (i < 63)
                w2f = *(const bf16x8*)&W2f[(((long)i * 8 + wv) * 64 + lane) * 8];
        }
        if (n == (i & 15)) {
            if (wv == (i >> 4)) {          // r = i  (mu)
#pragma unroll
                for (int r = 0; r < 4; ++r) zred[aq * 4 + r][0] = zacc[r];
            }
            if (wv == 4 + (i >> 4)) {      // r = 64 + i  (sigma)
#pragma unroll
                for (int r = 0; r < 4; ++r) zred[aq * 4 + r][1] = zacc[r];
            }
        }
        __syncthreads();   // C: zred visible

        // ---- X: every thread computes x for its own row (= lane&15), kept in register ----
        {
            const float mu = zred[n][0] + b2m;
            const float sg = zred[n][1] + b2s;
            const float xnew = uL[n][i] * __expf(sg) + mu;
            xreg = xnew;
            ldj += sg;
            if (t < 16) xLs[t][i] = xnew;
        }
        // no barrier needed: next writers of h1g/zred are separated by barriers A/B of step i+1
    }

    __syncthreads();
    if (t < 256) {
        int r = t >> 4, c = (t & 15) * 4;
        float4 v;
        v.x = xLs[r][c]; v.y = xLs[r][c + 1]; v.z = xLs[r][c + 2]; v.w = xLs[r][c + 3];
        *(float4*)&out[(long)(rowbase + r) * 64 + c] = v;
    }
    if (t < 16) out[(long)BATCH * 64 + rowbase + t] = ldj;   // row n == t
}

extern "C" void kernel_launch(void* const* d_in, const int* in_sizes, int n_in,
                              void* d_out, int out_size, void* d_ws, size_t ws_size,
                              hipStream_t stream) {
    (void)in_sizes; (void)n_in; (void)out_size; (void)ws_size;
    const float* u  = (const float*)d_in[0];
    const float* W0 = (const float*)d_in[1];
    const float* b0 = (const float*)d_in[2];
    const float* W1 = (const float*)d_in[3];
    const float* b1 = (const float*)d_in[4];
    const float* W2 = (const float*)d_in[5];
    const float* b2 = (const float*)d_in[6];
    float* out = (float*)d_out;

    // d_ws layout (bytes)
    short* W1f = (short*)d_ws;                                   // 4,128,768 B
    short* W2f = (short*)((char*)d_ws + 4128768);                //   516,096 B
    short* W0p = (short*)((char*)d_ws + 4128768 + 516096);       //   131,072 B
    float* b0p = (float*)((char*)d_ws + 4128768 + 516096 + 131072);          // 4 KB
    float* b1p = (float*)((char*)d_ws + 4128768 + 516096 + 131072 + 4096);   // 4 KB

    long blocks = (PREP_TOTAL + 255) / 256;
    prep2<<<dim3((unsigned)blocks), dim3(256), 0, stream>>>(W0, b0, W1, b1, W2,
                                                            W1f, W2f, W0p, b0p, b1p);
    made2<<<dim3(BATCH / 16), dim3(NTHR), 0, stream>>>(u, b2, W1f, W2f, W0p, b0p, b1p, out);
}

// Round 3
// 227.017 us; speedup vs baseline: 1.4368x; 1.0564x over previous
//
#include <hip/hip_runtime.h>
#include <hip/hip_bf16.h>

#define BATCH 4096
#define NTHR 512

typedef __attribute__((ext_vector_type(8))) short bf16x8;
typedef __attribute__((ext_vector_type(4))) float f32x4;
typedef __attribute__((ext_vector_type(4))) short short4v;

// CK-style barrier: drain LDS only, leave global loads in flight (no vmcnt(0))
#define BAR() asm volatile("s_waitcnt lgkmcnt(0)\n\ts_barrier" ::: "memory")

// dh-sorted packing: group g (= degree) has cnt(g) units, prefix off1(g)
__host__ __device__ __forceinline__ int off1(int g) { return (g <= 16) ? 17 * g : 16 * g + 16; }
__host__ __device__ __forceinline__ int cntg(int g) { return (g < 16) ? 17 : 16; }
// packed slot p -> original unit index u = gp + 63*jp
__host__ __device__ __forceinline__ int unitOf(int p) {
    int gp, jp;
    if (p < 272) { gp = p / 17; jp = p - gp * 17; }
    else         { gp = (p >> 4) - 1; jp = p & 15; }
    return gp + 63 * jp;
}
__device__ __forceinline__ short f2bf(float f) {
    __hip_bfloat16 h = __float2bfloat16(f);
    return *reinterpret_cast<short*>(&h);
}

// ---------------- prep3: LDS-staged coalesced packing ----------------
// W1f [g][tile(64)][lane(64)][e(8)] bf16 : B[k=(lane>>4)*8+e][n=lane&15], p=tile*16+n,
//     value = k<cnt(g) ? W1[unitOf(p)][g+63k] : 0
// W2f [g][wave(8)][lane(64)][e(8)] bf16 : r = wave*16+n, value = k<cnt(g) ? W2[r][g+63k] : 0
// W0p [d(64)][p(1024)] bf16 : W0[unitOf(p)][d];  b0p/b1p [1024] f32 packed biases
// grid: 80 blocks x 256 thr. blocks 0-63: W1f tile b; 64-71: W2f w=b-64; 72-79: W0p slices (+biases on 72)
__global__ void prep3(const float* __restrict__ W0, const float* __restrict__ b0,
                      const float* __restrict__ W1, const float* __restrict__ b1,
                      const float* __restrict__ W2,
                      short* __restrict__ W1f, short* __restrict__ W2f,
                      short* __restrict__ W0p, float* __restrict__ b0p,
                      float* __restrict__ b1p) {
    __shared__ short ws[16][1024];   // 32 KB bf16 stage
    const int b = blockIdx.x, t = threadIdx.x;

    if (b < 72) {
        const bool isW1 = (b < 64);
        const int n = t >> 4;                 // staged row 0..15
        const int u = isW1 ? unitOf(b * 16 + n) : ((b - 64) * 16 + n);
        const float* src = isW1 ? (W1 + (long)u * 1024) : (W2 + (long)u * 1024);
        const int c0 = (t & 15) * 4;
#pragma unroll
        for (int j = 0; j < 16; ++j) {
            int c = c0 + j * 64;
            float4 v = *(const float4*)&src[c];
            short4v sv;
            sv[0] = f2bf(v.x); sv[1] = f2bf(v.y); sv[2] = f2bf(v.z); sv[3] = f2bf(v.w);
            *(short4v*)&ws[n][c] = sv;
        }
        __syncthreads();
#pragma unroll 1
        for (int it = 0; it < 16; ++it) {
            int v = t + it * 256;             // 0..4095, need 4032
            if (v < 4032) {
                int g = v >> 6, lane = v & 63;
                int nn = lane & 15, aq = lane >> 4;
                bf16x8 pk;
#pragma unroll
                for (int e = 0; e < 8; ++e) {
                    int k = aq * 8 + e;
                    pk[e] = (k < cntg(g)) ? ws[nn][g + 63 * k] : (short)0;
                }
                if (isW1) *(bf16x8*)&W1f[(((long)g * 64 + b) * 64 + lane) * 8] = pk;
                else      *(bf16x8*)&W2f[(((long)g * 8 + (b - 64)) * 64 + lane) * 8] = pk;
            }
        }
    } else {
        const int bb = b - 72;                // 0..7, each 8192 elements of W0p
#pragma unroll 1
        for (int j = 0; j < 32; ++j) {
            int q = bb * 8192 + t + j * 256;
            int p = q & 1023, d = q >> 10;
            W0p[q] = f2bf(W0[(long)unitOf(p) * 64 + d]);
        }
        if (bb == 0) {
            for (int p = t; p < 1024; p += 256) {
                int u = unitOf(p);
                b0p[p] = b0[u];
                b1p[p] = b1[u];
            }
        }
    }
}

// ---------------- made3: incremental MFMA pipeline, raw barriers, bias-in-acc ----------------
__global__ __launch_bounds__(NTHR) void made3(
    const float* __restrict__ uin, const float* __restrict__ b2,
    const short* __restrict__ W1f, const short* __restrict__ W2f,
    const short* __restrict__ W0p, const float* __restrict__ b0p,
    const float* __restrict__ b1p, float* __restrict__ out) {

    __shared__ __align__(16) short h1g[16][40];   // group-g h1 (bf16), A-frag layout, K-pad zeroed
    __shared__ __align__(16) short h2g[16][40];   // group-g h2 (bf16)
    __shared__ float uL[16][65];                  // preloaded u
    __shared__ float xLs[16][65];                 // x staged for final coalesced store
    __shared__ float zred[16][2];                 // published (mu, sigma) incl. bias

    const int t = threadIdx.x, lane = t & 63, wv = t >> 6;
    const int n = lane & 15, aq = lane >> 4;
    const int rowbase = blockIdx.x * 16;

    {   // zero h1g/h2g (K-pad cols 17..31 must read 0 forever)
        int* z1 = (int*)&h1g[0][0]; int* z2 = (int*)&h2g[0][0];
        for (int idx = t; idx < 16 * 40 / 2; idx += NTHR) { z1[idx] = 0; z2[idx] = 0; }
    }
    if (t < 256) {
        int r = t >> 4, c = (t & 15) * 4;
        float4 v = *(const float4*)&uin[(long)(rowbase + r) * 64 + c];
        uL[r][c] = v.x; uL[r][c + 1] = v.y; uL[r][c + 2] = v.z; uL[r][c + 3] = v.w;
    }

    // strided tile ownership: wave wv owns tiles wv, wv+8, ..., wv+56 (balanced tail)
    // accumulators carry the bias from init (finalize = relu(acc) only)
    f32x4 acc1[8], acc2[8], zacc;
#pragma unroll
    for (int s = 0; s < 8; ++s) {
        const int p = (wv + 8 * s) * 16 + n;
        const float bb0 = b0p[p], bb1 = b1p[p];
        acc1[s] = (f32x4){bb0, bb0, bb0, bb0};
        acc2[s] = (f32x4){bb1, bb1, bb1, bb1};
    }
    {
        const float bz = b2[wv * 16 + n];     // z column r = wv*16+n
        zacc = (f32x4){bz, bz, bz, bz};
    }

    // prefetch registers (re-issued right after each consumption; never drained at barriers)
    bf16x8 w1f[8]; bf16x8 w2f; short w0s[8];
#pragma unroll
    for (int s = 0; s < 8; ++s) {
        const int tile = wv + 8 * s;
        w0s[s] = W0p[tile * 16 + n];                                        // d=0
        w1f[s] = *(const bf16x8*)&W1f[(((long)0 * 64 + tile) * 64 + lane) * 8]; // g=0
    }
    w2f = *(const bf16x8*)&W2f[(((long)0 * 8 + wv) * 64 + lane) * 8];       // g=0

    float xreg = 0.f, ldj = 0.f;
    BAR();

#pragma unroll 1
    for (int i = 0; i < 64; ++i) {
        const int g = i - 1;
        const int og = (g >= 0) ? off1(g) : 0;
        const int cg = (g >= 0) ? cntg(g) : 0;
        const float uv = uL[n][i];            // issued early, used in X phase

        // ---- S1: pre1 += x_{i-1} (rank-1 MFMA), finalize h1 group g ----
        if (g >= 0) {
            bf16x8 af = {0, 0, 0, 0, 0, 0, 0, 0};
            if (aq == 0) af[0] = f2bf(xreg);      // A[m][k=0] = x[m]
#pragma unroll
            for (int s = 0; s < 8; ++s) {
                const int tile = wv + 8 * s;
                if (tile * 16 + 16 > og) {
                    bf16x8 bfr = {0, 0, 0, 0, 0, 0, 0, 0};
                    if (aq == 0) bfr[0] = w0s[s]; // B[0][n] = W0 row d=i-1
                    acc1[s] = __builtin_amdgcn_mfma_f32_16x16x32_bf16(af, bfr, acc1[s], 0, 0, 0);
                }
            }
#pragma unroll
            for (int s = 0; s < 8; ++s)           // prefetch W0 row d=i (consumed step i+1)
                w0s[s] = W0p[i * 1024 + (wv + 8 * s) * 16 + n];
#pragma unroll
            for (int s = 0; s < 8; ++s) {         // finalize: relu(acc) -> h1g
                const int tile = wv + 8 * s;
                const int p = tile * 16 + n;
                if (p >= og && p < og + 17) {
                    const int j = p - og;
#pragma unroll
                    for (int r = 0; r < 4; ++r) {
                        float v = (j < cg) ? acc1[s][r] : 0.f;
                        v = v > 0.f ? v : 0.f;
                        h1g[aq * 4 + r][j] = f2bf(v);
                    }
                }
            }
        }
        BAR();   // A: h1g visible

        // ---- S2: pre2 += h1_group_g * W1 (active tiles), finalize h2 group g ----
        if (g >= 0) {
            const bf16x8 af2 = *(const bf16x8*)&h1g[n][aq * 8];
#pragma unroll
            for (int s = 0; s < 8; ++s) {
                const int tile = wv + 8 * s;
                if (tile * 16 + 16 > og)
                    acc2[s] = __builtin_amdgcn_mfma_f32_16x16x32_bf16(af2, w1f[s], acc2[s], 0, 0, 0);
            }
            {   // prefetch W1f for g'=i (clamped; only future-active tiles)
                const int gp = (i < 63) ? i : 62;
                const int ogn = off1(gp);
#pragma unroll
                for (int s = 0; s < 8; ++s) {
                    const int tile = wv + 8 * s;
                    if (tile * 16 + 16 > ogn)
                        w1f[s] = *(const bf16x8*)&W1f[(((long)gp * 64 + tile) * 64 + lane) * 8];
                }
            }
#pragma unroll
            for (int s = 0; s < 8; ++s) {
                const int tile = wv + 8 * s;
                const int p = tile * 16 + n;
                if (p >= og && p < og + 17) {
                    const int j = p - og;
#pragma unroll
                    for (int r = 0; r < 4; ++r) {
                        float v = (j < cg) ? acc2[s][r] : 0.f;
                        v = v > 0.f ? v : 0.f;
                        h2g[aq * 4 + r][j] = f2bf(v);
                    }
                }
            }
        }
        BAR();   // B: h2g visible

        // ---- S3: zacc += h2_group_g * W2 (one MFMA/wave), publish mu_i/sigma_i ----
        if (g >= 0) {
            const bf16x8 af3 = *(const bf16x8*)&h2g[n][aq * 8];
            zacc = __builtin_amdgcn_mfma_f32_16x16x32_bf16(af3, w2f, zacc, 0, 0, 0);
            const int gp = (i < 63) ? i : 62;
            w2f = *(const bf16x8*)&W2f[(((long)gp * 8 + wv) * 64 + lane) * 8];
        }
        if (n == (i & 15)) {
            if (wv == (i >> 4)) {            // z column r = i  (mu, bias included)
#pragma unroll
                for (int r = 0; r < 4; ++r) zred[aq * 4 + r][0] = zacc[r];
            }
            if (wv == 4 + (i >> 4)) {        // z column r = 64+i  (sigma, bias included)
#pragma unroll
                for (int r = 0; r < 4; ++r) zred[aq * 4 + r][1] = zacc[r];
            }
        }
        BAR();   // C: zred visible

        // ---- X: every thread computes x for its own row (= lane&15) ----
        {
            const float mu = zred[n][0];
            const float sg = zred[n][1];
            const float xnew = uv * __expf(sg) + mu;
            xreg = xnew;
            ldj += sg;
            if (t < 16) xLs[t][i] = xnew;
        }
        // no barrier: next h1g/zred writers are separated by BAR A/B of step i+1
    }

    BAR();
    if (t < 256) {
        int r = t >> 4, c = (t & 15) * 4;
        float4 v;
        v.x = xLs[r][c]; v.y = xLs[r][c + 1]; v.z = xLs[r][c + 2]; v.w = xLs[r][c + 3];
        *(float4*)&out[(long)(rowbase + r) * 64 + c] = v;
    }
    if (t < 16) out[(long)BATCH * 64 + rowbase + t] = ldj;   // thread t has row n == t
}

extern "C" void kernel_launch(void* const* d_in, const int* in_sizes, int n_in,
                              void* d_out, int out_size, void* d_ws, size_t ws_size,
                              hipStream_t stream) {
    (void)in_sizes; (void)n_in; (void)out_size; (void)ws_size;
    const float* u  = (const float*)d_in[0];
    const float* W0 = (const float*)d_in[1];
    const float* b0 = (const float*)d_in[2];
    const float* W1 = (const float*)d_in[3];
    const float* b1 = (const float*)d_in[4];
    const float* W2 = (const float*)d_in[5];
    const float* b2 = (const float*)d_in[6];
    float* out = (float*)d_out;

    // d_ws layout (bytes)
    short* W1f = (short*)d_ws;                                               // 4,128,768 B
    short* W2f = (short*)((char*)d_ws + 4128768);                            //   516,096 B
    short* W0p = (short*)((char*)d_ws + 4128768 + 516096);                   //   131,072 B
    float* b0p = (float*)((char*)d_ws + 4128768 + 516096 + 131072);          //     4 KB
    float* b1p = (float*)((char*)d_ws + 4128768 + 516096 + 131072 + 4096);   //     4 KB

    prep3<<<dim3(80), dim3(256), 0, stream>>>(W0, b0, W1, b1, W2, W1f, W2f, W0p, b0p, b1p);
    made3<<<dim3(BATCH / 16), dim3(NTHR), 0, stream>>>(u, b2, W1f, W2f, W0p, b0p, b1p, out);
}